// Round 1
// baseline (1554.596 us; speedup 1.0000x reference)
//
#include <hip/hip_runtime.h>

#define NB 2   // batch
#define NG 4   // groups

__device__ __forceinline__ float sigmoidf_(float x) { return 1.f / (1.f + __expf(-x)); }

// ---------------- weight repack kernels (make innermost index contiguous) -------------
// off_w (18,32,3,3) -> [ic][k][oc]  (32*9*18)
__global__ void repack_off_w(const float* __restrict__ src, float* __restrict__ dst) {
    int i = blockIdx.x * 256 + threadIdx.x;
    if (i >= 32 * 9 * 18) return;
    int oc = i % 18, k = (i / 18) % 9, ic = i / 162;
    dst[i] = src[oc * 288 + ic * 9 + k];
}
// mod_w (36,64,3,3) -> [ic][k][oc]  (64*9*36)
__global__ void repack_mod_w(const float* __restrict__ src, float* __restrict__ dst) {
    int i = blockIdx.x * 256 + threadIdx.x;
    if (i >= 64 * 9 * 36) return;
    int oc = i % 36, k = (i / 36) % 9, ic = i / 324;
    dst[i] = src[oc * 576 + ic * 9 + k];
}
// reg_w (64,64,3,3) -> [g][k][c][o]  (4*9*16*64)
__global__ void repack_reg_w(const float* __restrict__ src, float* __restrict__ dst) {
    int i = blockIdx.x * 256 + threadIdx.x;
    if (i >= 36864) return;
    int o = i % 64, c = (i / 64) % 16, k = (i / 1024) % 9, g = i / 9216;
    dst[i] = src[o * 576 + (g * 16 + c) * 9 + k];
}

// ---------------- transpose sou (b,64,H,W) -> xt (b,g,HW,16) --------------------------
__global__ __launch_bounds__(256) void transpose_kernel(const float* __restrict__ x,
                                                        float* __restrict__ xt, int HW) {
    __shared__ float tile[256][17];
    const int t = threadIdx.x;
    const int q0 = blockIdx.x * 256;
    const int g = blockIdx.y, b = blockIdx.z;
    const float* src = x + (size_t)(b * 64 + g * 16) * HW + q0;
#pragma unroll
    for (int c = 0; c < 16; ++c) tile[t][c] = src[(size_t)c * HW + t];
    __syncthreads();
    float4* dst = (float4*)(xt + ((size_t)(b * NG + g) * HW + q0) * 16);
#pragma unroll
    for (int j = 0; j < 4; ++j) {
        int f4 = j * 256 + t;
        int q = f4 >> 2, c4 = (f4 & 3) * 4;
        dst[f4] = make_float4(tile[q][c4], tile[q][c4 + 1], tile[q][c4 + 2], tile[q][c4 + 3]);
    }
}

// ---------------- offset conv: concat(sou_g, ref_g) 32ch -> 18ch, + sigmoid map -------
__global__ __launch_bounds__(256) void offset_conv_kernel(
    const float* __restrict__ sou, const float* __restrict__ ref,
    const float* __restrict__ wt /*[ic][k][oc]*/, const float* __restrict__ bias,
    float* __restrict__ offm, int H, int W, float rng) {
    __shared__ float tile[8][18][18];
    const int tx = threadIdx.x, ty = threadIdx.y;
    const int tid = ty * 16 + tx;
    const int w0 = blockIdx.x * 16, h0 = blockIdx.y * 16;
    const int g = blockIdx.z & 3, b = blockIdx.z >> 2;
    const int HW = H * W;
    float acc[18];
#pragma unroll
    for (int i = 0; i < 18; ++i) acc[i] = 0.f;
    for (int cc = 0; cc < 32; cc += 8) {
        __syncthreads();
        for (int idx = tid; idx < 8 * 324; idx += 256) {
            int j = idx / 324;
            int rem = idx - j * 324;
            int r = rem / 18, ccol = rem - r * 18;
            int ic = cc + j;
            const float* src = (ic < 16) ? (sou + (size_t)(b * 64 + g * 16 + ic) * HW)
                                         : (ref + (size_t)(b * 64 + g * 16 + ic - 16) * HW);
            int y = h0 - 1 + r, x = w0 - 1 + ccol;
            tile[j][r][ccol] = (y >= 0 && y < H && x >= 0 && x < W) ? src[y * W + x] : 0.f;
        }
        __syncthreads();
#pragma unroll
        for (int j = 0; j < 8; ++j) {
#pragma unroll
            for (int ky = 0; ky < 3; ++ky) {
#pragma unroll
                for (int kx = 0; kx < 3; ++kx) {
                    float v = tile[j][ty + ky][tx + kx];
                    const float* wp = wt + ((cc + j) * 9 + ky * 3 + kx) * 18;
#pragma unroll
                    for (int oc = 0; oc < 18; ++oc) acc[oc] = fmaf(v, wp[oc], acc[oc]);
                }
            }
        }
    }
    const int q = (h0 + ty) * W + (w0 + tx);
#pragma unroll
    for (int oc = 0; oc < 18; ++oc) {
        float v = acc[oc] + bias[oc];
        offm[(size_t)(b * 72 + g * 18 + oc) * HW + q] = rng * (2.f * sigmoidf_(v) - 1.f);
    }
}

// ---------------- modulator conv: 64ch -> 36ch, 2*sigmoid -----------------------------
__global__ __launch_bounds__(256) void mod_conv_kernel(
    const float* __restrict__ sou, const float* __restrict__ wt /*[ic][k][oc]*/,
    const float* __restrict__ bias, float* __restrict__ mod, int H, int W) {
    __shared__ float tile[8][18][18];
    const int tx = threadIdx.x, ty = threadIdx.y;
    const int tid = ty * 16 + tx;
    const int w0 = blockIdx.x * 16, h0 = blockIdx.y * 16;
    const int b = blockIdx.z;
    const int HW = H * W;
    float acc[36];
#pragma unroll
    for (int i = 0; i < 36; ++i) acc[i] = 0.f;
    for (int cc = 0; cc < 64; cc += 8) {
        __syncthreads();
        for (int idx = tid; idx < 8 * 324; idx += 256) {
            int j = idx / 324;
            int rem = idx - j * 324;
            int r = rem / 18, ccol = rem - r * 18;
            const float* src = sou + (size_t)(b * 64 + cc + j) * HW;
            int y = h0 - 1 + r, x = w0 - 1 + ccol;
            tile[j][r][ccol] = (y >= 0 && y < H && x >= 0 && x < W) ? src[y * W + x] : 0.f;
        }
        __syncthreads();
#pragma unroll
        for (int j = 0; j < 8; ++j) {
#pragma unroll
            for (int ky = 0; ky < 3; ++ky) {
#pragma unroll
                for (int kx = 0; kx < 3; ++kx) {
                    float v = tile[j][ty + ky][tx + kx];
                    const float* wp = wt + ((cc + j) * 9 + ky * 3 + kx) * 36;
#pragma unroll
                    for (int oc = 0; oc < 36; ++oc) acc[oc] = fmaf(v, wp[oc], acc[oc]);
                }
            }
        }
    }
    const int q = (h0 + ty) * W + (w0 + tx);
#pragma unroll
    for (int oc = 0; oc < 36; ++oc)
        mod[(size_t)(b * 36 + oc) * HW + q] = 2.f * sigmoidf_(acc[oc] + bias[oc]);
}

// ---------------- deformable conv main kernel ----------------------------------------
template <int OTILE>
__global__ __launch_bounds__(64) void deform_kernel(
    const float* __restrict__ xt, const float* __restrict__ offm,
    const float* __restrict__ mod, const float* __restrict__ wt /*[g][k][c][o]*/,
    float* __restrict__ out, int H, int logW) {
    const int W = 1 << logW;
    const int HW = H * W;
    const int q = blockIdx.x * 64 + threadIdx.x;
    const int o0 = blockIdx.y * OTILE;
    const int b = blockIdx.z;
    const int h = q >> logW, xpix = q & (W - 1);
    float acc[OTILE];
#pragma unroll
    for (int o = 0; o < OTILE; ++o) acc[o] = 0.f;
    for (int g = 0; g < 4; ++g) {
        const float* xg = xt + (size_t)(b * NG + g) * HW * 16;
        const float* og = offm + (size_t)(b * 72 + g * 18) * HW + q;
        const float* mg = mod + (size_t)(b * 36 + g * 9) * HW + q;
#pragma unroll
        for (int k = 0; k < 9; ++k) {
            const int ky = k / 3, kx = k - ky * 3;
            float dy = og[(size_t)(2 * k) * HW];
            float dx = og[(size_t)(2 * k + 1) * HW];
            float m = mg[(size_t)k * HW];
            float py = (float)(h - 1 + ky) + dy;
            float px = (float)(xpix - 1 + kx) + dx;
            float y0f = floorf(py), x0f = floorf(px);
            float wy = py - y0f, wx = px - x0f;
            int y0 = (int)y0f, x0 = (int)x0f;
            float s[16];
#pragma unroll
            for (int c = 0; c < 16; ++c) s[c] = 0.f;
#pragma unroll
            for (int cor = 0; cor < 4; ++cor) {
                int yy = y0 + (cor >> 1), xx = x0 + (cor & 1);
                float cw = ((cor >> 1) ? wy : 1.f - wy) * ((cor & 1) ? wx : 1.f - wx);
                cw = (yy >= 0 && yy < H && xx >= 0 && xx < W) ? cw * m : 0.f;
                int yc = min(max(yy, 0), H - 1), xc = min(max(xx, 0), W - 1);
                const float4* p = (const float4*)(xg + (size_t)(yc * W + xc) * 16);
                float4 v0 = p[0], v1 = p[1], v2 = p[2], v3 = p[3];
                s[0] = fmaf(cw, v0.x, s[0]);  s[1] = fmaf(cw, v0.y, s[1]);
                s[2] = fmaf(cw, v0.z, s[2]);  s[3] = fmaf(cw, v0.w, s[3]);
                s[4] = fmaf(cw, v1.x, s[4]);  s[5] = fmaf(cw, v1.y, s[5]);
                s[6] = fmaf(cw, v1.z, s[6]);  s[7] = fmaf(cw, v1.w, s[7]);
                s[8] = fmaf(cw, v2.x, s[8]);  s[9] = fmaf(cw, v2.y, s[9]);
                s[10] = fmaf(cw, v2.z, s[10]); s[11] = fmaf(cw, v2.w, s[11]);
                s[12] = fmaf(cw, v3.x, s[12]); s[13] = fmaf(cw, v3.y, s[13]);
                s[14] = fmaf(cw, v3.z, s[14]); s[15] = fmaf(cw, v3.w, s[15]);
            }
            const float* wp = wt + (g * 9 + k) * 1024 + o0;
#pragma unroll
            for (int c = 0; c < 16; ++c) {
#pragma unroll
                for (int o = 0; o < OTILE; ++o)
                    acc[o] = fmaf(s[c], wp[c * 64 + o], acc[o]);
            }
        }
    }
#pragma unroll
    for (int o = 0; o < OTILE; ++o)
        out[(size_t)(b * 64 + o0 + o) * HW + q] = acc[o];
}

// ---------------- mean of dy / dx channels -------------------------------------------
__global__ __launch_bounds__(256) void mean_kernel(const float* __restrict__ offm,
                                                   float* __restrict__ mean, int HW) {
    const int q = blockIdx.x * 256 + threadIdx.x;
    const int b = blockIdx.y;
    const float* p = offm + (size_t)b * 72 * HW + q;
    float sy = 0.f, sx = 0.f;
#pragma unroll
    for (int j = 0; j < 36; ++j) {
        sy += p[(size_t)(2 * j) * HW];
        sx += p[(size_t)(2 * j + 1) * HW];
    }
    mean[(size_t)(b * 2) * HW + q] = sy * (1.f / 36.f);
    mean[(size_t)(b * 2 + 1) * HW + q] = sx * (1.f / 36.f);
}

// ---------------- align_corners bilinear upsample to 512x512, * fs --------------------
__global__ __launch_bounds__(256) void upsample_kernel(const float* __restrict__ mean,
                                                       float* __restrict__ out, int H, int W,
                                                       float fs) {
    const int idx = blockIdx.x * 256 + threadIdx.x;  // 512*512 plane
    const int yo = idx >> 9, xo = idx & 511;
    const int c = blockIdx.y, b = blockIdx.z;
    const float sc = (float)(H - 1) * (1.f / 511.f);
    float sy = yo * sc, sx = xo * sc;
    int y0 = min((int)sy, H - 2), x0 = min((int)sx, W - 2);
    float wy = sy - (float)y0, wx = sx - (float)x0;
    const float* m = mean + (size_t)(b * 2 + c) * H * W;
    float v00 = m[y0 * W + x0], v01 = m[y0 * W + x0 + 1];
    float v10 = m[(y0 + 1) * W + x0], v11 = m[(y0 + 1) * W + x0 + 1];
    float r0 = v00 * (1.f - wy) + v10 * wy;   // interp y first (matches reference)
    float r1 = v01 * (1.f - wy) + v11 * wy;
    out[((size_t)(b * 2 + c) * 512 + yo) * 512 + xo] = (r0 * (1.f - wx) + r1 * wx) * fs;
}

extern "C" void kernel_launch(void* const* d_in, const int* in_sizes, int n_in,
                              void* d_out, int out_size, void* d_ws, size_t ws_size,
                              hipStream_t stream) {
    const float* fin[21];
    for (int i = 0; i < 21; ++i) fin[i] = (const float*)d_in[i];
    // dict order: sou1,ref1,sou2,ref2,sou3,ref3  |  arg order: sou1,sou2,sou3,ref1,ref2,ref3
    const float *sou[3], *ref[3];
    if (in_sizes[1] == in_sizes[0]) {
        sou[0] = fin[0]; ref[0] = fin[1];
        sou[1] = fin[2]; ref[1] = fin[3];
        sou[2] = fin[4]; ref[2] = fin[5];
    } else {
        sou[0] = fin[0]; sou[1] = fin[1]; sou[2] = fin[2];
        ref[0] = fin[3]; ref[1] = fin[4]; ref[2] = fin[5];
    }
    float* out = (float*)d_out;
    float* ws = (float*)d_ws;
    // workspace layout (floats), sized for level 1 and reused for all levels
    float* XT = ws;                   // 2*64*16384   = 2097152
    float* OFFM = ws + 2097152;       // 2*72*16384   = 2359296
    float* MOD = ws + 4456448;        // 2*36*16384   = 1179648
    float* MEAN = ws + 5636096;       // 2*2*16384    = 65536
    float* RWT = ws + 5701632;        // 36864
    float* OWT = RWT + 36864;         // 5184
    float* MWT = OWT + 5184;          // 20736

    const int Hs[3] = {128, 64, 32};
    const int logWs[3] = {7, 6, 5};
    const float fss[3] = {4.f, 8.f, 16.f};
    float* fouts[3] = {out + 655360, out + 131072, out};
    float* oouts[3] = {out + 4849664, out + 3801088, out + 2752512};

    for (int lvl = 2; lvl >= 0; --lvl) {  // level 3, 2, 1 (reference order; independent)
        const int H = Hs[lvl], W = H, HW = H * W;
        const float* ow = fin[6 + lvl * 5 + 0];
        const float* ob = fin[6 + lvl * 5 + 1];
        const float* mw = fin[6 + lvl * 5 + 2];
        const float* mb = fin[6 + lvl * 5 + 3];
        const float* rw = fin[6 + lvl * 5 + 4];
        const float rng = 0.25f * (float)H;

        repack_off_w<<<dim3((5184 + 255) / 256), 256, 0, stream>>>(ow, OWT);
        repack_mod_w<<<dim3((20736 + 255) / 256), 256, 0, stream>>>(mw, MWT);
        repack_reg_w<<<dim3(144), 256, 0, stream>>>(rw, RWT);
        transpose_kernel<<<dim3(HW / 256, NG, NB), 256, 0, stream>>>(sou[lvl], XT, HW);
        offset_conv_kernel<<<dim3(W / 16, H / 16, NB * NG), dim3(16, 16), 0, stream>>>(
            sou[lvl], ref[lvl], OWT, ob, OFFM, H, W, rng);
        mod_conv_kernel<<<dim3(W / 16, H / 16, NB), dim3(16, 16), 0, stream>>>(
            sou[lvl], MWT, mb, MOD, H, W);
        if (lvl == 0)
            deform_kernel<32><<<dim3(HW / 64, 2, NB), 64, 0, stream>>>(XT, OFFM, MOD, RWT,
                                                                       fouts[lvl], H, logWs[lvl]);
        else if (lvl == 1)
            deform_kernel<16><<<dim3(HW / 64, 4, NB), 64, 0, stream>>>(XT, OFFM, MOD, RWT,
                                                                       fouts[lvl], H, logWs[lvl]);
        else
            deform_kernel<8><<<dim3(HW / 64, 8, NB), 64, 0, stream>>>(XT, OFFM, MOD, RWT,
                                                                      fouts[lvl], H, logWs[lvl]);
        mean_kernel<<<dim3(HW / 256, NB), 256, 0, stream>>>(OFFM, MEAN, HW);
        upsample_kernel<<<dim3(1024, 2, NB), 256, 0, stream>>>(MEAN, oouts[lvl], H, W, fss[lvl]);
    }
}

// Round 2
// 955.188 us; speedup vs baseline: 1.6275x; 1.6275x over previous
//
#include <hip/hip_runtime.h>

#define NB 2   // batch
#define NG 4   // groups

__device__ __forceinline__ float sigmoidf_(float x) { return 1.f / (1.f + __expf(-x)); }
__device__ __forceinline__ unsigned bf16rne(float x) {
    unsigned b = __float_as_uint(x);
    return (b + 0x7FFFu + ((b >> 16) & 1u)) >> 16;
}

// ---------------- weight repack kernels -----------------------------------------------
// off_w (18,32,3,3) -> [ic][k][oc18]
__global__ void repack_off_w(const float* __restrict__ src, float* __restrict__ dst) {
    int i = blockIdx.x * 256 + threadIdx.x;
    if (i >= 32 * 9 * 18) return;
    int oc = i % 18, k = (i / 18) % 9, ic = i / 162;
    dst[i] = src[oc * 288 + ic * 9 + k];
}
// mod_w (36,64,3,3) -> [ic][k][oc36]
__global__ void repack_mod_w(const float* __restrict__ src, float* __restrict__ dst) {
    int i = blockIdx.x * 256 + threadIdx.x;
    if (i >= 64 * 9 * 36) return;
    int oc = i % 36, k = (i / 36) % 9, ic = i / 324;
    dst[i] = src[oc * 576 + ic * 9 + k];
}
// reg_w (64,64,3,3) -> [g][k][c16][o64]
__global__ void repack_reg_w(const float* __restrict__ src, float* __restrict__ dst) {
    int i = blockIdx.x * 256 + threadIdx.x;
    if (i >= 36864) return;
    int o = i % 64, c = (i / 64) % 16, k = (i / 1024) % 9, g = i / 9216;
    dst[i] = src[o * 576 + (g * 16 + c) * 9 + k];
}

// ---------------- transpose sou (b,64,H,W) -> xt (b,g,HW,16) --------------------------
__global__ __launch_bounds__(256) void transpose_kernel(const float* __restrict__ x,
                                                        float* __restrict__ xt, int HW) {
    __shared__ float tile[256][17];
    const int t = threadIdx.x;
    const int q0 = blockIdx.x * 256;
    const int g = blockIdx.y, b = blockIdx.z;
    const float* src = x + (size_t)(b * 64 + g * 16) * HW + q0;
#pragma unroll
    for (int c = 0; c < 16; ++c) tile[t][c] = src[(size_t)c * HW + t];
    __syncthreads();
    float4* dst = (float4*)(xt + ((size_t)(b * NG + g) * HW + q0) * 16);
#pragma unroll
    for (int j = 0; j < 4; ++j) {
        int f4 = j * 256 + t;
        int q = f4 >> 2, c4 = (f4 & 3) * 4;
        dst[f4] = make_float4(tile[q][c4], tile[q][c4 + 1], tile[q][c4 + 2], tile[q][c4 + 3]);
    }
}

// ---------------- offset conv: thread-per-pixel, 18 oc accumulators -------------------
__global__ __launch_bounds__(256) void offset_conv_kernel(
    const float* __restrict__ sou, const float* __restrict__ ref,
    const float* __restrict__ wt /*[ic][k][18]*/, const float* __restrict__ bias,
    float* __restrict__ offm, int H, int logW, float rng) {
    const int W = 1 << logW, HW = H * W;
    const int g = blockIdx.y, b = blockIdx.z;
    const int q = blockIdx.x * 256 + threadIdx.x;
    const int h = q >> logW, x = q & (W - 1);
    float acc[18];
#pragma unroll
    for (int i = 0; i < 18; ++i) acc[i] = 0.f;
    const float* base_s = sou + (size_t)(b * 64 + g * 16) * HW;
    const float* base_r = ref + (size_t)(b * 64 + g * 16) * HW;
    for (int ic = 0; ic < 32; ++ic) {
        const float* plane = (ic < 16) ? base_s + (size_t)ic * HW : base_r + (size_t)(ic - 16) * HW;
        const float* wp = wt + ic * 162;
#pragma unroll
        for (int ky = 0; ky < 3; ++ky) {
            int yy = h + ky - 1;
            bool yok = (yy >= 0) && (yy < H);
            const float* row = plane + (size_t)min(max(yy, 0), H - 1) * W;
#pragma unroll
            for (int kx = 0; kx < 3; ++kx) {
                int xx = x + kx - 1;
                bool ok = yok && (xx >= 0) && (xx < W);
                float v = ok ? row[min(max(xx, 0), W - 1)] : 0.f;
                const float* wk = wp + (ky * 3 + kx) * 18;
#pragma unroll
                for (int oc = 0; oc < 18; ++oc) acc[oc] = fmaf(v, wk[oc], acc[oc]);
            }
        }
    }
#pragma unroll
    for (int oc = 0; oc < 18; ++oc) {
        float v = acc[oc] + bias[oc];
        offm[(size_t)(b * 72 + g * 18 + oc) * HW + q] = rng * (2.f * sigmoidf_(v) - 1.f);
    }
}

// ---------------- modulator conv: 4 waves/block split 36 oc ---------------------------
__global__ __launch_bounds__(256) void mod_conv_kernel(
    const float* __restrict__ sou, const float* __restrict__ wt /*[ic][k][36]*/,
    const float* __restrict__ bias, float* __restrict__ mod, int H, int logW) {
    const int W = 1 << logW, HW = H * W;
    const int b = blockIdx.y;
    const int wv = threadIdx.x >> 6, lane = threadIdx.x & 63;
    const int q = blockIdx.x * 64 + lane;
    const int h = q >> logW, x = q & (W - 1);
    const int o0 = wv * 9;
    float acc[9];
#pragma unroll
    for (int i = 0; i < 9; ++i) acc[i] = 0.f;
    const float* base = sou + (size_t)b * 64 * HW;
    for (int ic = 0; ic < 64; ++ic) {
        const float* plane = base + (size_t)ic * HW;
        const float* wp = wt + ic * 324 + o0;
#pragma unroll
        for (int ky = 0; ky < 3; ++ky) {
            int yy = h + ky - 1;
            bool yok = (yy >= 0) && (yy < H);
            const float* row = plane + (size_t)min(max(yy, 0), H - 1) * W;
#pragma unroll
            for (int kx = 0; kx < 3; ++kx) {
                int xx = x + kx - 1;
                bool ok = yok && (xx >= 0) && (xx < W);
                float v = ok ? row[min(max(xx, 0), W - 1)] : 0.f;
                const float* wk = wp + (ky * 3 + kx) * 36;
#pragma unroll
                for (int oc = 0; oc < 9; ++oc) acc[oc] = fmaf(v, wk[oc], acc[oc]);
            }
        }
    }
#pragma unroll
    for (int oc = 0; oc < 9; ++oc)
        mod[(size_t)(b * 36 + o0 + oc) * HW + q] = 2.f * sigmoidf_(acc[oc] + bias[o0 + oc]);
}

// ---------------- gather: one thread per (b, g, k, pixel) -> S bf16 pairs -------------
__global__ __launch_bounds__(256) void gather_kernel(
    const float* __restrict__ xt, const float* __restrict__ offm,
    const float* __restrict__ mod, unsigned* __restrict__ S, int H, int logW) {
    const int W = 1 << logW, HW = H * W;
    const int gk = blockIdx.y;  // g*9+k
    const int g = gk / 9, k = gk - g * 9;
    const int b = blockIdx.z;
    const int q = blockIdx.x * 256 + threadIdx.x;
    const int h = q >> logW, xp = q & (W - 1);
    const int ky = k / 3, kx = k - ky * 3;
    float dy = offm[(size_t)(b * 72 + g * 18 + 2 * k) * HW + q];
    float dx = offm[(size_t)(b * 72 + g * 18 + 2 * k + 1) * HW + q];
    float m = mod[(size_t)(b * 36 + g * 9 + k) * HW + q];
    float py = (float)(h - 1 + ky) + dy;
    float px = (float)(xp - 1 + kx) + dx;
    float y0f = floorf(py), x0f = floorf(px);
    float wy = py - y0f, wx = px - x0f;
    int y0 = (int)y0f, x0 = (int)x0f;
    const float* xg = xt + (size_t)(b * NG + g) * HW * 16;
    float s[16];
#pragma unroll
    for (int c = 0; c < 16; ++c) s[c] = 0.f;
#pragma unroll
    for (int cor = 0; cor < 4; ++cor) {
        int yy = y0 + (cor >> 1), xx = x0 + (cor & 1);
        float cw = ((cor >> 1) ? wy : 1.f - wy) * ((cor & 1) ? wx : 1.f - wx);
        cw = (yy >= 0 && yy < H && xx >= 0 && xx < W) ? cw * m : 0.f;
        int yc = min(max(yy, 0), H - 1), xc = min(max(xx, 0), W - 1);
        const float4* p = (const float4*)(xg + (size_t)((yc << logW) + xc) * 16);
        float4 v0 = p[0], v1 = p[1], v2 = p[2], v3 = p[3];
        s[0] = fmaf(cw, v0.x, s[0]);   s[1] = fmaf(cw, v0.y, s[1]);
        s[2] = fmaf(cw, v0.z, s[2]);   s[3] = fmaf(cw, v0.w, s[3]);
        s[4] = fmaf(cw, v1.x, s[4]);   s[5] = fmaf(cw, v1.y, s[5]);
        s[6] = fmaf(cw, v1.z, s[6]);   s[7] = fmaf(cw, v1.w, s[7]);
        s[8] = fmaf(cw, v2.x, s[8]);   s[9] = fmaf(cw, v2.y, s[9]);
        s[10] = fmaf(cw, v2.z, s[10]); s[11] = fmaf(cw, v2.w, s[11]);
        s[12] = fmaf(cw, v3.x, s[12]); s[13] = fmaf(cw, v3.y, s[13]);
        s[14] = fmaf(cw, v3.z, s[14]); s[15] = fmaf(cw, v3.w, s[15]);
    }
    unsigned* Sp = S + (size_t)(b * 288 + gk * 8) * HW + q;
#pragma unroll
    for (int pr = 0; pr < 8; ++pr) {
        unsigned u = bf16rne(s[2 * pr]) | (bf16rne(s[2 * pr + 1]) << 16);
        Sp[(size_t)pr * HW] = u;
    }
}

// ---------------- deform GEMM: K=576 (288 bf16-pair rows), LDS-staged S ---------------
__global__ __launch_bounds__(256) void dgemm_kernel(
    const unsigned* __restrict__ S, const float* __restrict__ wt /*[g][k][c][64]*/,
    float* __restrict__ out, int HW) {
    __shared__ unsigned lds[288 * 64];  // 72 KB
    const int b = blockIdx.y;
    const int q0 = blockIdx.x * 64;
    const int tid = threadIdx.x;
    const int wv = tid >> 6, lane = tid & 63;
    const unsigned* Sb = S + (size_t)b * 288 * HW + q0;
    for (int i = tid; i < 288 * 16; i += 256) {
        int r = i >> 4, ch = (i & 15) << 2;
        *(uint4*)&lds[r * 64 + ch] = *(const uint4*)(Sb + (size_t)r * HW + ch);
    }
    __syncthreads();
    float acc[16];
#pragma unroll
    for (int o = 0; o < 16; ++o) acc[o] = 0.f;
    const float* wbase = wt + wv * 16;
#pragma unroll 4
    for (int r = 0; r < 288; ++r) {
        unsigned u = lds[r * 64 + lane];
        float flo = __uint_as_float(u << 16);
        float fhi = __uint_as_float(u & 0xFFFF0000u);
        const float* wp = wbase + r * 128;
#pragma unroll
        for (int o = 0; o < 16; ++o) acc[o] = fmaf(flo, wp[o], acc[o]);
#pragma unroll
        for (int o = 0; o < 16; ++o) acc[o] = fmaf(fhi, wp[64 + o], acc[o]);
    }
    float* op = out + (size_t)(b * 64 + wv * 16) * HW + q0 + lane;
#pragma unroll
    for (int o = 0; o < 16; ++o) op[(size_t)o * HW] = acc[o];
}

// ---------------- mean of dy / dx channels -------------------------------------------
__global__ __launch_bounds__(256) void mean_kernel(const float* __restrict__ offm,
                                                   float* __restrict__ mean, int HW) {
    const int q = blockIdx.x * 256 + threadIdx.x;
    const int b = blockIdx.y;
    const float* p = offm + (size_t)b * 72 * HW + q;
    float sy = 0.f, sx = 0.f;
#pragma unroll
    for (int j = 0; j < 36; ++j) {
        sy += p[(size_t)(2 * j) * HW];
        sx += p[(size_t)(2 * j + 1) * HW];
    }
    mean[(size_t)(b * 2) * HW + q] = sy * (1.f / 36.f);
    mean[(size_t)(b * 2 + 1) * HW + q] = sx * (1.f / 36.f);
}

// ---------------- align_corners bilinear upsample to 512x512, * fs --------------------
__global__ __launch_bounds__(256) void upsample_kernel(const float* __restrict__ mean,
                                                       float* __restrict__ out, int H, int W,
                                                       float fs) {
    const int idx = blockIdx.x * 256 + threadIdx.x;
    const int yo = idx >> 9, xo = idx & 511;
    const int c = blockIdx.y, b = blockIdx.z;
    const float sc = (float)(H - 1) * (1.f / 511.f);
    float sy = yo * sc, sx = xo * sc;
    int y0 = min((int)sy, H - 2), x0 = min((int)sx, W - 2);
    float wy = sy - (float)y0, wx = sx - (float)x0;
    const float* m = mean + (size_t)(b * 2 + c) * H * W;
    float v00 = m[y0 * W + x0], v01 = m[y0 * W + x0 + 1];
    float v10 = m[(y0 + 1) * W + x0], v11 = m[(y0 + 1) * W + x0 + 1];
    float r0 = v00 * (1.f - wy) + v10 * wy;
    float r1 = v01 * (1.f - wy) + v11 * wy;
    out[((size_t)(b * 2 + c) * 512 + yo) * 512 + xo] = (r0 * (1.f - wx) + r1 * wx) * fs;
}

extern "C" void kernel_launch(void* const* d_in, const int* in_sizes, int n_in,
                              void* d_out, int out_size, void* d_ws, size_t ws_size,
                              hipStream_t stream) {
    const float* fin[21];
    for (int i = 0; i < 21; ++i) fin[i] = (const float*)d_in[i];
    const float *sou[3], *ref[3];
    if (in_sizes[1] == in_sizes[0]) {
        sou[0] = fin[0]; ref[0] = fin[1];
        sou[1] = fin[2]; ref[1] = fin[3];
        sou[2] = fin[4]; ref[2] = fin[5];
    } else {
        sou[0] = fin[0]; sou[1] = fin[1]; sou[2] = fin[2];
        ref[0] = fin[3]; ref[1] = fin[4]; ref[2] = fin[5];
    }
    float* out = (float*)d_out;
    float* ws = (float*)d_ws;
    // workspace layout (float indices), reused across levels (sized for lvl 1 = 128x128)
    float* XT = ws;                     // 2*4*16384*16 = 2097152
    float* OFFM = ws + 2097152;         // 2*72*16384   = 2359296
    float* MOD = ws + 4456448;          // 2*36*16384   = 1179648
    float* MEAN = ws + 5636096;         // 65536
    float* RWT = ws + 5701632;          // 36864
    float* OWT = RWT + 36864;           // 5184
    float* MWT = OWT + 5184;            // 20736
    unsigned* S = (unsigned*)(ws + 5764416);  // 2*288*16384 uints = 9437184 (~37.7 MB)

    const int Hs[3] = {128, 64, 32};
    const int logWs[3] = {7, 6, 5};
    const float fss[3] = {4.f, 8.f, 16.f};
    float* fouts[3] = {out + 655360, out + 131072, out};
    float* oouts[3] = {out + 4849664, out + 3801088, out + 2752512};

    for (int lvl = 2; lvl >= 0; --lvl) {
        const int H = Hs[lvl], W = H, HW = H * W, logW = logWs[lvl];
        const float* ow = fin[6 + lvl * 5 + 0];
        const float* ob = fin[6 + lvl * 5 + 1];
        const float* mw = fin[6 + lvl * 5 + 2];
        const float* mb = fin[6 + lvl * 5 + 3];
        const float* rw = fin[6 + lvl * 5 + 4];
        const float rng = 0.25f * (float)H;

        repack_off_w<<<dim3(21), 256, 0, stream>>>(ow, OWT);
        repack_mod_w<<<dim3(81), 256, 0, stream>>>(mw, MWT);
        repack_reg_w<<<dim3(144), 256, 0, stream>>>(rw, RWT);
        transpose_kernel<<<dim3(HW / 256, NG, NB), 256, 0, stream>>>(sou[lvl], XT, HW);
        offset_conv_kernel<<<dim3(HW / 256, NG, NB), 256, 0, stream>>>(
            sou[lvl], ref[lvl], OWT, ob, OFFM, H, logW, rng);
        mod_conv_kernel<<<dim3(HW / 64, NB), 256, 0, stream>>>(sou[lvl], MWT, mb, MOD, H, logW);
        gather_kernel<<<dim3(HW / 256, 36, NB), 256, 0, stream>>>(XT, OFFM, MOD, S, H, logW);
        dgemm_kernel<<<dim3(HW / 64, NB), 256, 0, stream>>>(S, RWT, fouts[lvl], HW);
        mean_kernel<<<dim3(HW / 256, NB), 256, 0, stream>>>(OFFM, MEAN, HW);
        upsample_kernel<<<dim3(1024, 2, NB), 256, 0, stream>>>(MEAN, oouts[lvl], H, W, fss[lvl]);
    }
}

// Round 3
// 763.208 us; speedup vs baseline: 2.0369x; 1.2515x over previous
//
#include <hip/hip_runtime.h>

#define NB 2   // batch
#define NG 4   // groups

__device__ __forceinline__ float sigmoidf_(float x) { return 1.f / (1.f + __expf(-x)); }
__device__ __forceinline__ unsigned bf16rne(float x) {
    unsigned b = __float_as_uint(x);
    return (b + 0x7FFFu + ((b >> 16) & 1u)) >> 16;
}

// ---------------- fused weight repack: all 3 levels, all 3 tensors --------------------
// off_w (18,32,3,3) -> [ic][k][oc18]   (5184)
// mod_w (36,64,3,3) -> [ic][k][oc36]   (20736)
// reg_w (64,64,3,3) -> [g][k][c16][o64] (36864)
__global__ __launch_bounds__(256) void repack_all(
    const float* __restrict__ ow0, const float* __restrict__ mw0, const float* __restrict__ rw0,
    const float* __restrict__ ow1, const float* __restrict__ mw1, const float* __restrict__ rw1,
    const float* __restrict__ ow2, const float* __restrict__ mw2, const float* __restrict__ rw2,
    float* __restrict__ dst /* per lvl: [36864 reg][5184 off][20736 mod] */) {
    const int lvl = blockIdx.y;
    const float* ow = lvl == 0 ? ow0 : (lvl == 1 ? ow1 : ow2);
    const float* mw = lvl == 0 ? mw0 : (lvl == 1 ? mw1 : mw2);
    const float* rw = lvl == 0 ? rw0 : (lvl == 1 ? rw1 : rw2);
    float* d = dst + lvl * 62784;
    int i = blockIdx.x * 256 + threadIdx.x;
    if (i < 36864) {  // reg
        int o = i % 64, c = (i / 64) % 16, k = (i / 1024) % 9, g = i / 9216;
        d[i] = rw[o * 576 + (g * 16 + c) * 9 + k];
    }
    if (i < 5184) {   // off
        int oc = i % 18, k = (i / 18) % 9, ic = i / 162;
        d[36864 + i] = ow[oc * 288 + ic * 9 + k];
    }
    if (i < 20736) {  // mod
        int oc = i % 36, k = (i / 36) % 9, ic = i / 324;
        d[42048 + i] = mw[oc * 576 + ic * 9 + k];
    }
}

// ---------------- transpose sou (b,64,H,W) -> xt (b,g,HW,16) --------------------------
__global__ __launch_bounds__(256) void transpose_kernel(const float* __restrict__ x,
                                                        float* __restrict__ xt, int HW) {
    __shared__ float tile[256][17];
    const int t = threadIdx.x;
    const int q0 = blockIdx.x * 256;
    const int g = blockIdx.y, b = blockIdx.z;
    const float* src = x + (size_t)(b * 64 + g * 16) * HW + q0;
#pragma unroll
    for (int c = 0; c < 16; ++c) tile[t][c] = src[(size_t)c * HW + t];
    __syncthreads();
    float4* dst = (float4*)(xt + ((size_t)(b * NG + g) * HW + q0) * 16);
#pragma unroll
    for (int j = 0; j < 4; ++j) {
        int f4 = j * 256 + t;
        int q = f4 >> 2, c4 = (f4 & 3) * 4;
        dst[f4] = make_float4(tile[q][c4], tile[q][c4 + 1], tile[q][c4 + 2], tile[q][c4 + 3]);
    }
}

// ---------------- offset conv: thread-per-pixel, 18 oc accumulators -------------------
__global__ __launch_bounds__(256) void offset_conv_kernel(
    const float* __restrict__ sou, const float* __restrict__ ref,
    const float* __restrict__ wt /*[ic][k][18]*/, const float* __restrict__ bias,
    float* __restrict__ offm, int H, int logW, float rng) {
    const int W = 1 << logW, HW = H * W;
    const int g = blockIdx.y, b = blockIdx.z;
    const int q = blockIdx.x * 256 + threadIdx.x;
    const int h = q >> logW, x = q & (W - 1);
    float acc[18];
#pragma unroll
    for (int i = 0; i < 18; ++i) acc[i] = 0.f;
    const float* base_s = sou + (size_t)(b * 64 + g * 16) * HW;
    const float* base_r = ref + (size_t)(b * 64 + g * 16) * HW;
    for (int ic = 0; ic < 32; ++ic) {
        const float* plane = (ic < 16) ? base_s + (size_t)ic * HW : base_r + (size_t)(ic - 16) * HW;
        const float* wp = wt + ic * 162;
#pragma unroll
        for (int ky = 0; ky < 3; ++ky) {
            int yy = h + ky - 1;
            bool yok = (yy >= 0) && (yy < H);
            const float* row = plane + (size_t)min(max(yy, 0), H - 1) * W;
#pragma unroll
            for (int kx = 0; kx < 3; ++kx) {
                int xx = x + kx - 1;
                bool ok = yok && (xx >= 0) && (xx < W);
                float v = ok ? row[min(max(xx, 0), W - 1)] : 0.f;
                const float* wk = wp + (ky * 3 + kx) * 18;
#pragma unroll
                for (int oc = 0; oc < 18; ++oc) acc[oc] = fmaf(v, wk[oc], acc[oc]);
            }
        }
    }
#pragma unroll
    for (int oc = 0; oc < 18; ++oc) {
        float v = acc[oc] + bias[oc];
        offm[(size_t)(b * 72 + g * 18 + oc) * HW + q] = rng * (2.f * sigmoidf_(v) - 1.f);
    }
}

// ---------------- modulator conv: 4 waves/block split 36 oc (uniform weight base) -----
__global__ __launch_bounds__(256) void mod_conv_kernel(
    const float* __restrict__ sou, const float* __restrict__ wt /*[ic][k][36]*/,
    const float* __restrict__ bias, float* __restrict__ mod, int H, int logW) {
    const int W = 1 << logW, HW = H * W;
    const int b = blockIdx.y;
    const int o0 = __builtin_amdgcn_readfirstlane((int)threadIdx.x >> 6) * 9;  // uniform!
    const int lane = threadIdx.x & 63;
    const int q = blockIdx.x * 64 + lane;
    const int h = q >> logW, x = q & (W - 1);
    float acc[9];
#pragma unroll
    for (int i = 0; i < 9; ++i) acc[i] = 0.f;
    const float* base = sou + (size_t)b * 64 * HW;
    for (int ic = 0; ic < 64; ++ic) {
        const float* plane = base + (size_t)ic * HW;
        const float* wp = wt + ic * 324 + o0;
#pragma unroll
        for (int ky = 0; ky < 3; ++ky) {
            int yy = h + ky - 1;
            bool yok = (yy >= 0) && (yy < H);
            const float* row = plane + (size_t)min(max(yy, 0), H - 1) * W;
#pragma unroll
            for (int kx = 0; kx < 3; ++kx) {
                int xx = x + kx - 1;
                bool ok = yok && (xx >= 0) && (xx < W);
                float v = ok ? row[min(max(xx, 0), W - 1)] : 0.f;
                const float* wk = wp + (ky * 3 + kx) * 36;
#pragma unroll
                for (int oc = 0; oc < 9; ++oc) acc[oc] = fmaf(v, wk[oc], acc[oc]);
            }
        }
    }
#pragma unroll
    for (int oc = 0; oc < 9; ++oc)
        mod[(size_t)(b * 36 + o0 + oc) * HW + q] = 2.f * sigmoidf_(acc[oc] + bias[o0 + oc]);
}

// ---------------- gather: one thread per (b, g, k, pixel) -> S bf16 pairs -------------
__global__ __launch_bounds__(256) void gather_kernel(
    const float* __restrict__ xt, const float* __restrict__ offm,
    const float* __restrict__ mod, unsigned* __restrict__ S, int H, int logW) {
    const int W = 1 << logW, HW = H * W;
    const int gk = blockIdx.y;  // g*9+k
    const int g = gk / 9, k = gk - g * 9;
    const int b = blockIdx.z;
    const int q = blockIdx.x * 256 + threadIdx.x;
    const int h = q >> logW, xp = q & (W - 1);
    const int ky = k / 3, kx = k - ky * 3;
    float dy = offm[(size_t)(b * 72 + g * 18 + 2 * k) * HW + q];
    float dx = offm[(size_t)(b * 72 + g * 18 + 2 * k + 1) * HW + q];
    float m = mod[(size_t)(b * 36 + g * 9 + k) * HW + q];
    float py = (float)(h - 1 + ky) + dy;
    float px = (float)(xp - 1 + kx) + dx;
    float y0f = floorf(py), x0f = floorf(px);
    float wy = py - y0f, wx = px - x0f;
    int y0 = (int)y0f, x0 = (int)x0f;
    const float* xg = xt + (size_t)(b * NG + g) * HW * 16;
    float s[16];
#pragma unroll
    for (int c = 0; c < 16; ++c) s[c] = 0.f;
#pragma unroll
    for (int cor = 0; cor < 4; ++cor) {
        int yy = y0 + (cor >> 1), xx = x0 + (cor & 1);
        float cw = ((cor >> 1) ? wy : 1.f - wy) * ((cor & 1) ? wx : 1.f - wx);
        cw = (yy >= 0 && yy < H && xx >= 0 && xx < W) ? cw * m : 0.f;
        int yc = min(max(yy, 0), H - 1), xc = min(max(xx, 0), W - 1);
        const float4* p = (const float4*)(xg + (size_t)((yc << logW) + xc) * 16);
        float4 v0 = p[0], v1 = p[1], v2 = p[2], v3 = p[3];
        s[0] = fmaf(cw, v0.x, s[0]);   s[1] = fmaf(cw, v0.y, s[1]);
        s[2] = fmaf(cw, v0.z, s[2]);   s[3] = fmaf(cw, v0.w, s[3]);
        s[4] = fmaf(cw, v1.x, s[4]);   s[5] = fmaf(cw, v1.y, s[5]);
        s[6] = fmaf(cw, v1.z, s[6]);   s[7] = fmaf(cw, v1.w, s[7]);
        s[8] = fmaf(cw, v2.x, s[8]);   s[9] = fmaf(cw, v2.y, s[9]);
        s[10] = fmaf(cw, v2.z, s[10]); s[11] = fmaf(cw, v2.w, s[11]);
        s[12] = fmaf(cw, v3.x, s[12]); s[13] = fmaf(cw, v3.y, s[13]);
        s[14] = fmaf(cw, v3.z, s[14]); s[15] = fmaf(cw, v3.w, s[15]);
    }
    unsigned* Sp = S + (size_t)(b * 288 + gk * 8) * HW + q;
#pragma unroll
    for (int pr = 0; pr < 8; ++pr) {
        unsigned u = bf16rne(s[2 * pr]) | (bf16rne(s[2 * pr + 1]) << 16);
        Sp[(size_t)pr * HW] = u;
    }
}

// ---------------- deform GEMM: K=576 (288 bf16-pair rows), LDS-staged S ---------------
__global__ __launch_bounds__(256) void dgemm_kernel(
    const unsigned* __restrict__ S, const float* __restrict__ wt /*[g][k][c][64]*/,
    float* __restrict__ out, int HW) {
    __shared__ unsigned lds[288 * 64];  // 72 KB
    const int b = blockIdx.y;
    const int q0 = blockIdx.x * 64;
    const int tid = threadIdx.x;
    const int wvu = __builtin_amdgcn_readfirstlane(tid >> 6);  // uniform wave id!
    const int lane = tid & 63;
    const unsigned* Sb = S + (size_t)b * 288 * HW + q0;
    for (int i = tid; i < 288 * 16; i += 256) {
        int r = i >> 4, ch = (i & 15) << 2;
        *(uint4*)&lds[r * 64 + ch] = *(const uint4*)(Sb + (size_t)r * HW + ch);
    }
    __syncthreads();
    float acc[16];
#pragma unroll
    for (int o = 0; o < 16; ++o) acc[o] = 0.f;
    const float* wbase = wt + wvu * 16;
#pragma unroll 2
    for (int r = 0; r < 288; ++r) {
        unsigned u = lds[r * 64 + lane];
        float flo = __uint_as_float(u << 16);
        float fhi = __uint_as_float(u & 0xFFFF0000u);
        const float* wp = wbase + r * 128;
#pragma unroll
        for (int o = 0; o < 16; ++o) acc[o] = fmaf(flo, wp[o], acc[o]);
#pragma unroll
        for (int o = 0; o < 16; ++o) acc[o] = fmaf(fhi, wp[64 + o], acc[o]);
    }
    float* op = out + (size_t)(b * 64 + wvu * 16) * HW + q0 + lane;
#pragma unroll
    for (int o = 0; o < 16; ++o) op[(size_t)o * HW] = acc[o];
}

// ---------------- mean of dy / dx channels -------------------------------------------
__global__ __launch_bounds__(256) void mean_kernel(const float* __restrict__ offm,
                                                   float* __restrict__ mean, int HW) {
    const int q = blockIdx.x * 256 + threadIdx.x;
    const int b = blockIdx.y;
    const float* p = offm + (size_t)b * 72 * HW + q;
    float sy = 0.f, sx = 0.f;
#pragma unroll
    for (int j = 0; j < 36; ++j) {
        sy += p[(size_t)(2 * j) * HW];
        sx += p[(size_t)(2 * j + 1) * HW];
    }
    mean[(size_t)(b * 2) * HW + q] = sy * (1.f / 36.f);
    mean[(size_t)(b * 2 + 1) * HW + q] = sx * (1.f / 36.f);
}

// ---------------- align_corners bilinear upsample to 512x512, * fs --------------------
__global__ __launch_bounds__(256) void upsample_kernel(const float* __restrict__ mean,
                                                       float* __restrict__ out, int H, int W,
                                                       float fs) {
    const int idx = blockIdx.x * 256 + threadIdx.x;
    const int yo = idx >> 9, xo = idx & 511;
    const int c = blockIdx.y, b = blockIdx.z;
    const float sc = (float)(H - 1) * (1.f / 511.f);
    float sy = yo * sc, sx = xo * sc;
    int y0 = min((int)sy, H - 2), x0 = min((int)sx, W - 2);
    float wy = sy - (float)y0, wx = sx - (float)x0;
    const float* m = mean + (size_t)(b * 2 + c) * H * W;
    float v00 = m[y0 * W + x0], v01 = m[y0 * W + x0 + 1];
    float v10 = m[(y0 + 1) * W + x0], v11 = m[(y0 + 1) * W + x0 + 1];
    float r0 = v00 * (1.f - wy) + v10 * wy;
    float r1 = v01 * (1.f - wy) + v11 * wy;
    out[((size_t)(b * 2 + c) * 512 + yo) * 512 + xo] = (r0 * (1.f - wx) + r1 * wx) * fs;
}

extern "C" void kernel_launch(void* const* d_in, const int* in_sizes, int n_in,
                              void* d_out, int out_size, void* d_ws, size_t ws_size,
                              hipStream_t stream) {
    const float* fin[21];
    for (int i = 0; i < 21; ++i) fin[i] = (const float*)d_in[i];
    const float *sou[3], *ref[3];
    if (in_sizes[1] == in_sizes[0]) {
        sou[0] = fin[0]; ref[0] = fin[1];
        sou[1] = fin[2]; ref[1] = fin[3];
        sou[2] = fin[4]; ref[2] = fin[5];
    } else {
        sou[0] = fin[0]; sou[1] = fin[1]; sou[2] = fin[2];
        ref[0] = fin[3]; ref[1] = fin[4]; ref[2] = fin[5];
    }
    float* out = (float*)d_out;
    float* ws = (float*)d_ws;
    // workspace layout (float indices), reused across levels (sized for lvl 1 = 128x128)
    float* XT = ws;                     // 2*4*16384*16 = 2097152
    float* OFFM = ws + 2097152;         // 2*72*16384   = 2359296
    float* MOD = ws + 4456448;          // 2*36*16384   = 1179648
    float* MEAN = ws + 5636096;         // 65536
    float* WREP = ws + 5701632;         // 3 * 62784 = 188352  (per lvl: reg|off|mod)
    unsigned* S = (unsigned*)(ws + 5889984);  // 2*288*16384 uints = 9437184

    const int Hs[3] = {128, 64, 32};
    const int logWs[3] = {7, 6, 5};
    const float fss[3] = {4.f, 8.f, 16.f};
    float* fouts[3] = {out + 655360, out + 131072, out};
    float* oouts[3] = {out + 4849664, out + 3801088, out + 2752512};

    repack_all<<<dim3(144, 3), 256, 0, stream>>>(
        fin[6], fin[8], fin[10], fin[11], fin[13], fin[15], fin[16], fin[18], fin[20], WREP);

    for (int lvl = 2; lvl >= 0; --lvl) {
        const int H = Hs[lvl], W = H, HW = H * W, logW = logWs[lvl];
        const float* ob = fin[6 + lvl * 5 + 1];
        const float* mb = fin[6 + lvl * 5 + 3];
        const float* RWT = WREP + lvl * 62784;
        const float* OWT = RWT + 36864;
        const float* MWT = RWT + 42048;
        const float rng = 0.25f * (float)H;

        transpose_kernel<<<dim3(HW / 256, NG, NB), 256, 0, stream>>>(sou[lvl], XT, HW);
        offset_conv_kernel<<<dim3(HW / 256, NG, NB), 256, 0, stream>>>(
            sou[lvl], ref[lvl], OWT, ob, OFFM, H, logW, rng);
        mod_conv_kernel<<<dim3(HW / 64, NB), 256, 0, stream>>>(sou[lvl], MWT, mb, MOD, H, logW);
        gather_kernel<<<dim3(HW / 256, 36, NB), 256, 0, stream>>>(XT, OFFM, MOD, S, H, logW);
        dgemm_kernel<<<dim3(HW / 64, NB), 256, 0, stream>>>(S, RWT, fouts[lvl], HW);
        mean_kernel<<<dim3(HW / 256, NB), 256, 0, stream>>>(OFFM, MEAN, HW);
        upsample_kernel<<<dim3(1024, 2, NB), 256, 0, stream>>>(MEAN, oouts[lvl], H, W, fss[lvl]);
    }
}

// Round 4
// 638.115 us; speedup vs baseline: 2.4362x; 1.1960x over previous
//
#include <hip/hip_runtime.h>

__device__ __forceinline__ float sigmoidf_(float x) { return 1.f / (1.f + __expf(-x)); }
__device__ __forceinline__ unsigned bf16rne(float x) {
    unsigned b = __float_as_uint(x);
    return (b + 0x7FFFu + ((b >> 16) & 1u)) >> 16;
}

// ws layout (float words):
//   OFFM:  lvl0 @0 (2359296), lvl1 @2359296 (589824), lvl2 @2949120 (147456)
//   MOD:   lvl0 @3096576 (1179648), lvl1 @4276224 (294912), lvl2 @4571136 (73728)
//   MEAN:  lvl0 @4644864 (65536), lvl1 @4710400 (16384), lvl2 @4726784 (4096)
//   WREP:  @4730880, 3*62784 (per lvl: [36864 reg][5184 off][20736 mod])
//   S:     @4919232 (uints), lvl0 +0 (9437184), lvl1 +9437184 (2359296), lvl2 +11796480 (589824)
//   total 17305536 words = 69.2 MB
// XT lives in d_out's feat region (same size as feat, consumed in K2, overwritten in K3):
//   lvl0 @out+655360, lvl1 @out+131072, lvl2 @out+0

struct P {
    const float *sou0, *sou1, *sou2;
    const float *ref0, *ref1, *ref2;
    const float *ob0, *ob1, *ob2;
    const float *mb0, *mb1, *mb2;
    float* out;
    float* ws;
};

// ---------------- K0: fused weight repack (all levels) --------------------------------
__global__ __launch_bounds__(256) void repack_all(
    const float* __restrict__ ow0, const float* __restrict__ mw0, const float* __restrict__ rw0,
    const float* __restrict__ ow1, const float* __restrict__ mw1, const float* __restrict__ rw1,
    const float* __restrict__ ow2, const float* __restrict__ mw2, const float* __restrict__ rw2,
    float* __restrict__ dst) {
    const int lvl = blockIdx.y;
    const float* ow = lvl == 0 ? ow0 : (lvl == 1 ? ow1 : ow2);
    const float* mw = lvl == 0 ? mw0 : (lvl == 1 ? mw1 : mw2);
    const float* rw = lvl == 0 ? rw0 : (lvl == 1 ? rw1 : rw2);
    float* d = dst + lvl * 62784;
    int i = blockIdx.x * 256 + threadIdx.x;
    if (i < 36864) {  // reg -> [g][k][c16][o64]
        int o = i % 64, c = (i / 64) % 16, k = (i / 1024) % 9, g = i / 9216;
        d[i] = rw[o * 576 + (g * 16 + c) * 9 + k];
    }
    if (i < 5184) {   // off -> [ic][k][18]
        int oc = i % 18, k = (i / 18) % 9, ic = i / 162;
        d[36864 + i] = ow[oc * 288 + ic * 9 + k];
    }
    if (i < 20736) {  // mod -> [ic][k][36]
        int oc = i % 36, k = (i / 36) % 9, ic = i / 324;
        d[42048 + i] = mw[oc * 576 + ic * 9 + k];
    }
}

// ---------------- K1: offset_conv(672) + mod_conv(672) + transpose(672) ---------------
__global__ __launch_bounds__(256) void k1_prep(P p) {
    __shared__ float tile[256][17];
    const int t = blockIdx.x;
    int task, i;
    if (t < 672) { task = 0; i = t; }
    else if (t < 1344) { task = 1; i = t - 672; }
    else { task = 2; i = t - 1344; }
    int lvl, j;
    if (i < 512) { lvl = 0; j = i; }
    else if (i < 640) { lvl = 1; j = i - 512; }
    else { lvl = 2; j = i - 640; }
    const int logW = 7 - lvl;
    const int W = 1 << logW, H = W, HW = H * W;
    const float* sou = lvl == 0 ? p.sou0 : (lvl == 1 ? p.sou1 : p.sou2);
    float* ws = p.ws;
    float* OFFM = ws + (lvl == 0 ? 0 : (lvl == 1 ? 2359296 : 2949120));
    float* MOD = ws + (lvl == 0 ? 3096576 : (lvl == 1 ? 4276224 : 4571136));
    const float* WREP = ws + 4730880 + lvl * 62784;
    float* XT = p.out + (lvl == 0 ? 655360 : (lvl == 1 ? 131072 : 0));

    if (task == 0) {  // ---- offset conv: 32ch(concat) -> 18, sigmoid map
        const int nper = 64 >> (2 * lvl);
        const int qb = j % nper, g = (j / nper) & 3, b = j / (nper * 4);
        const int q = qb * 256 + threadIdx.x;
        const int h = q >> logW, x = q & (W - 1);
        const float* ref = lvl == 0 ? p.ref0 : (lvl == 1 ? p.ref1 : p.ref2);
        const float* wt = WREP + 36864;
        const float* bias = lvl == 0 ? p.ob0 : (lvl == 1 ? p.ob1 : p.ob2);
        const float rng = 0.25f * (float)H;
        float acc[18];
#pragma unroll
        for (int u = 0; u < 18; ++u) acc[u] = 0.f;
        const float* base_s = sou + (size_t)(b * 64 + g * 16) * HW;
        const float* base_r = ref + (size_t)(b * 64 + g * 16) * HW;
#pragma unroll 2
        for (int ic = 0; ic < 32; ++ic) {
            const float* plane = (ic < 16) ? base_s + (size_t)ic * HW : base_r + (size_t)(ic - 16) * HW;
            const float* wp = wt + ic * 162;
#pragma unroll
            for (int ky = 0; ky < 3; ++ky) {
                int yy = h + ky - 1;
                bool yok = (yy >= 0) && (yy < H);
                const float* row = plane + (size_t)min(max(yy, 0), H - 1) * W;
#pragma unroll
                for (int kx = 0; kx < 3; ++kx) {
                    int xx = x + kx - 1;
                    bool ok = yok && (xx >= 0) && (xx < W);
                    float v = ok ? row[min(max(xx, 0), W - 1)] : 0.f;
                    const float* wk = wp + (ky * 3 + kx) * 18;
#pragma unroll
                    for (int oc = 0; oc < 18; ++oc) acc[oc] = fmaf(v, wk[oc], acc[oc]);
                }
            }
        }
#pragma unroll
        for (int oc = 0; oc < 18; ++oc) {
            float v = acc[oc] + bias[oc];
            OFFM[(size_t)(b * 72 + g * 18 + oc) * HW + q] = rng * (2.f * sigmoidf_(v) - 1.f);
        }
    } else if (task == 1) {  // ---- modulator conv: 64 -> 36, 2*sigmoid, oc split by wave
        const int nper = 256 >> (2 * lvl);
        const int qb = j % nper, b = j / nper;
        const int o0 = __builtin_amdgcn_readfirstlane((int)threadIdx.x >> 6) * 9;
        const int lane = threadIdx.x & 63;
        const int q = qb * 64 + lane;
        const int h = q >> logW, x = q & (W - 1);
        const float* wt = WREP + 42048;
        const float* bias = lvl == 0 ? p.mb0 : (lvl == 1 ? p.mb1 : p.mb2);
        float acc[9];
#pragma unroll
        for (int u = 0; u < 9; ++u) acc[u] = 0.f;
        const float* base = sou + (size_t)b * 64 * HW;
#pragma unroll 2
        for (int ic = 0; ic < 64; ++ic) {
            const float* plane = base + (size_t)ic * HW;
            const float* wp = wt + ic * 324 + o0;
#pragma unroll
            for (int ky = 0; ky < 3; ++ky) {
                int yy = h + ky - 1;
                bool yok = (yy >= 0) && (yy < H);
                const float* row = plane + (size_t)min(max(yy, 0), H - 1) * W;
#pragma unroll
                for (int kx = 0; kx < 3; ++kx) {
                    int xx = x + kx - 1;
                    bool ok = yok && (xx >= 0) && (xx < W);
                    float v = ok ? row[min(max(xx, 0), W - 1)] : 0.f;
                    const float* wk = wp + (ky * 3 + kx) * 36;
#pragma unroll
                    for (int oc = 0; oc < 9; ++oc) acc[oc] = fmaf(v, wk[oc], acc[oc]);
                }
            }
        }
#pragma unroll
        for (int oc = 0; oc < 9; ++oc)
            MOD[(size_t)(b * 36 + o0 + oc) * HW + q] = 2.f * sigmoidf_(acc[oc] + bias[o0 + oc]);
    } else {  // ---- transpose (b,64,H,W) -> XT (b,g,HW,16)
        const int nper = 64 >> (2 * lvl);
        const int qb = j % nper, g = (j / nper) & 3, b = j / (nper * 4);
        const int tt = threadIdx.x;
        const int q0 = qb * 256;
        const float* src = sou + (size_t)(b * 64 + g * 16) * HW + q0;
#pragma unroll
        for (int c = 0; c < 16; ++c) tile[tt][c] = src[(size_t)c * HW + tt];
        __syncthreads();
        float4* dst = (float4*)(XT + ((size_t)(b * 4 + g) * HW + q0) * 16);
#pragma unroll
        for (int u = 0; u < 4; ++u) {
            int f4 = u * 256 + tt;
            int q = f4 >> 2, c4 = (f4 & 3) * 4;
            dst[f4] = make_float4(tile[q][c4], tile[q][c4 + 1], tile[q][c4 + 2], tile[q][c4 + 3]);
        }
    }
}

// ---------------- K2: gather(6048) + mean(168) ----------------------------------------
__global__ __launch_bounds__(256) void k2_gather(P p) {
    const int t = blockIdx.x;
    float* ws = p.ws;
    if (t < 6048) {
        int lvl, j;
        if (t < 4608) { lvl = 0; j = t; }
        else if (t < 5760) { lvl = 1; j = t - 4608; }
        else { lvl = 2; j = t - 5760; }
        const int logW = 7 - lvl;
        const int W = 1 << logW, H = W, HW = H * W;
        const int nper = 64 >> (2 * lvl);
        const int qb = j % nper, gk = (j / nper) % 36, b = j / (nper * 36);
        const int g = gk / 9, k = gk - g * 9;
        const float* OFFM = ws + (lvl == 0 ? 0 : (lvl == 1 ? 2359296 : 2949120));
        const float* MOD = ws + (lvl == 0 ? 3096576 : (lvl == 1 ? 4276224 : 4571136));
        const float* XT = p.out + (lvl == 0 ? 655360 : (lvl == 1 ? 131072 : 0));
        unsigned* S = (unsigned*)(ws + 4919232) + (lvl == 0 ? 0 : (lvl == 1 ? 9437184 : 11796480));
        const int q = qb * 256 + threadIdx.x;
        const int h = q >> logW, xp = q & (W - 1);
        const int ky = k / 3, kx = k - ky * 3;
        float dy = OFFM[(size_t)(b * 72 + g * 18 + 2 * k) * HW + q];
        float dx = OFFM[(size_t)(b * 72 + g * 18 + 2 * k + 1) * HW + q];
        float m = MOD[(size_t)(b * 36 + g * 9 + k) * HW + q];
        float py = (float)(h - 1 + ky) + dy;
        float px = (float)(xp - 1 + kx) + dx;
        float y0f = floorf(py), x0f = floorf(px);
        float wy = py - y0f, wx = px - x0f;
        int y0 = (int)y0f, x0 = (int)x0f;
        const float* xg = XT + (size_t)(b * 4 + g) * HW * 16;
        float s[16];
#pragma unroll
        for (int c = 0; c < 16; ++c) s[c] = 0.f;
#pragma unroll
        for (int cor = 0; cor < 4; ++cor) {
            int yy = y0 + (cor >> 1), xx = x0 + (cor & 1);
            float cw = ((cor >> 1) ? wy : 1.f - wy) * ((cor & 1) ? wx : 1.f - wx);
            cw = (yy >= 0 && yy < H && xx >= 0 && xx < W) ? cw * m : 0.f;
            int yc = min(max(yy, 0), H - 1), xc = min(max(xx, 0), W - 1);
            const float4* pp = (const float4*)(xg + (size_t)((yc << logW) + xc) * 16);
            float4 v0 = pp[0], v1 = pp[1], v2 = pp[2], v3 = pp[3];
            s[0] = fmaf(cw, v0.x, s[0]);   s[1] = fmaf(cw, v0.y, s[1]);
            s[2] = fmaf(cw, v0.z, s[2]);   s[3] = fmaf(cw, v0.w, s[3]);
            s[4] = fmaf(cw, v1.x, s[4]);   s[5] = fmaf(cw, v1.y, s[5]);
            s[6] = fmaf(cw, v1.z, s[6]);   s[7] = fmaf(cw, v1.w, s[7]);
            s[8] = fmaf(cw, v2.x, s[8]);   s[9] = fmaf(cw, v2.y, s[9]);
            s[10] = fmaf(cw, v2.z, s[10]); s[11] = fmaf(cw, v2.w, s[11]);
            s[12] = fmaf(cw, v3.x, s[12]); s[13] = fmaf(cw, v3.y, s[13]);
            s[14] = fmaf(cw, v3.z, s[14]); s[15] = fmaf(cw, v3.w, s[15]);
        }
        unsigned* Sp = S + (size_t)(b * 288 + gk * 8) * HW + q;
#pragma unroll
        for (int pr = 0; pr < 8; ++pr) {
            unsigned u = bf16rne(s[2 * pr]) | (bf16rne(s[2 * pr + 1]) << 16);
            Sp[(size_t)pr * HW] = u;
        }
    } else {
        int i = t - 6048;
        int lvl, j;
        if (i < 128) { lvl = 0; j = i; }
        else if (i < 160) { lvl = 1; j = i - 128; }
        else { lvl = 2; j = i - 160; }
        const int HW = 16384 >> (2 * lvl);
        const int nper = 64 >> (2 * lvl);
        const int qb = j % nper, b = j / nper;
        const float* OFFM = ws + (lvl == 0 ? 0 : (lvl == 1 ? 2359296 : 2949120));
        float* MEAN = ws + (lvl == 0 ? 4644864 : (lvl == 1 ? 4710400 : 4726784));
        const int q = qb * 256 + threadIdx.x;
        const float* pp = OFFM + (size_t)b * 72 * HW + q;
        float sy = 0.f, sx = 0.f;
#pragma unroll
        for (int u = 0; u < 36; ++u) {
            sy += pp[(size_t)(2 * u) * HW];
            sx += pp[(size_t)(2 * u + 1) * HW];
        }
        MEAN[(size_t)(b * 2) * HW + q] = sy * (1.f / 36.f);
        MEAN[(size_t)(b * 2 + 1) * HW + q] = sx * (1.f / 36.f);
    }
}

// ---------------- K3: dgemm(672) + upsample(3072) -------------------------------------
__global__ __launch_bounds__(256) void k3_out(P p) {
    __shared__ unsigned lds[288 * 64];  // 72 KB
    const int t = blockIdx.x;
    float* ws = p.ws;
    if (t < 672) {
        int lvl, j;
        if (t < 512) { lvl = 0; j = t; }
        else if (t < 640) { lvl = 1; j = t - 512; }
        else { lvl = 2; j = t - 640; }
        const int HW = 16384 >> (2 * lvl);
        const int nper = 256 >> (2 * lvl);
        const int qb = j % nper, b = j / nper;
        const unsigned* S = (const unsigned*)(ws + 4919232) +
                            (lvl == 0 ? 0 : (lvl == 1 ? 9437184 : 11796480));
        const float* wt = ws + 4730880 + lvl * 62784;
        float* outp = p.out + (lvl == 0 ? 655360 : (lvl == 1 ? 131072 : 0));
        const int q0 = qb * 64;
        const int tid = threadIdx.x;
        const int wvu = __builtin_amdgcn_readfirstlane(tid >> 6);
        const int lane = tid & 63;
        const unsigned* Sb = S + (size_t)b * 288 * HW + q0;
        for (int i = tid; i < 288 * 16; i += 256) {
            int r = i >> 4, ch = (i & 15) << 2;
            *(uint4*)&lds[r * 64 + ch] = *(const uint4*)(Sb + (size_t)r * HW + ch);
        }
        __syncthreads();
        float acc[16];
#pragma unroll
        for (int o = 0; o < 16; ++o) acc[o] = 0.f;
        const float* wbase = wt + wvu * 16;
#pragma unroll 2
        for (int r = 0; r < 288; ++r) {
            unsigned u = lds[r * 64 + lane];
            float flo = __uint_as_float(u << 16);
            float fhi = __uint_as_float(u & 0xFFFF0000u);
            const float* wp = wbase + r * 128;
#pragma unroll
            for (int o = 0; o < 16; ++o) acc[o] = fmaf(flo, wp[o], acc[o]);
#pragma unroll
            for (int o = 0; o < 16; ++o) acc[o] = fmaf(fhi, wp[64 + o], acc[o]);
        }
        float* op = outp + (size_t)(b * 64 + wvu * 16) * HW + q0 + lane;
#pragma unroll
        for (int o = 0; o < 16; ++o) op[(size_t)o * HW] = acc[o];
    } else {
        // upsample: 4 px/thread over flat [lvl][b][c][512][512]
        int i = t - 672;  // 0..3071
        int flat = (i * 256 + (int)threadIdx.x) * 4;
        int lvl = flat >> 20;
        int r = flat & 1048575;
        int b = r >> 19, c = (r >> 18) & 1;
        int pix = r & 262143;
        int yo = pix >> 9, xo = pix & 511;
        const int H = 128 >> lvl, W = H;
        const float* MEAN = ws + (lvl == 0 ? 4644864 : (lvl == 1 ? 4710400 : 4726784));
        const float* m = MEAN + (size_t)(b * 2 + c) * H * W;
        float* o = p.out + (lvl == 0 ? 4849664 : (lvl == 1 ? 3801088 : 2752512)) +
                   ((size_t)(b * 2 + c) * 512 + yo) * 512 + xo;
        const float fs = (float)(4 << lvl);
        const float sc = (float)(H - 1) * (1.f / 511.f);
        float sy = yo * sc;
        int y0 = min((int)sy, H - 2);
        float wy = sy - (float)y0;
        float rr[4];
#pragma unroll
        for (int u = 0; u < 4; ++u) {
            float sx = (float)(xo + u) * sc;
            int x0 = min((int)sx, W - 2);
            float wx = sx - (float)x0;
            float v00 = m[y0 * W + x0], v01 = m[y0 * W + x0 + 1];
            float v10 = m[(y0 + 1) * W + x0], v11 = m[(y0 + 1) * W + x0 + 1];
            float r0 = v00 * (1.f - wy) + v10 * wy;
            float r1 = v01 * (1.f - wy) + v11 * wy;
            rr[u] = (r0 * (1.f - wx) + r1 * wx) * fs;
        }
        *(float4*)o = make_float4(rr[0], rr[1], rr[2], rr[3]);
    }
}

extern "C" void kernel_launch(void* const* d_in, const int* in_sizes, int n_in,
                              void* d_out, int out_size, void* d_ws, size_t ws_size,
                              hipStream_t stream) {
    const float* fin[21];
    for (int i = 0; i < 21; ++i) fin[i] = (const float*)d_in[i];
    P p;
    if (in_sizes[1] == in_sizes[0]) {  // dict order sou1,ref1,sou2,ref2,sou3,ref3
        p.sou0 = fin[0]; p.ref0 = fin[1];
        p.sou1 = fin[2]; p.ref1 = fin[3];
        p.sou2 = fin[4]; p.ref2 = fin[5];
    } else {  // arg order
        p.sou0 = fin[0]; p.sou1 = fin[1]; p.sou2 = fin[2];
        p.ref0 = fin[3]; p.ref1 = fin[4]; p.ref2 = fin[5];
    }
    p.ob0 = fin[7]; p.mb0 = fin[9];
    p.ob1 = fin[12]; p.mb1 = fin[14];
    p.ob2 = fin[17]; p.mb2 = fin[19];
    p.out = (float*)d_out;
    p.ws = (float*)d_ws;

    repack_all<<<dim3(144, 3), 256, 0, stream>>>(
        fin[6], fin[8], fin[10], fin[11], fin[13], fin[15], fin[16], fin[18], fin[20],
        p.ws + 4730880);
    k1_prep<<<dim3(2016), 256, 0, stream>>>(p);
    k2_gather<<<dim3(6216), 256, 0, stream>>>(p);
    k3_out<<<dim3(3744), 256, 0, stream>>>(p);
}